// Round 8
// baseline (442.764 us; speedup 1.0000x reference)
//
#include <hip/hip_runtime.h>
#include <hip/hip_fp16.h>
#include <stdint.h>

#define PLANE_HALVES (512u * 512u * 32u)   // 8388608 halves = 16 MB per plane
#define NBUCKET 32768                       // 32x32x32 Morton cells

typedef _Float16 f16x8 __attribute__((ext_vector_type(8)));
typedef float    f32x4 __attribute__((ext_vector_type(4)));

// ---------------- transpose planes [C=32][512][512] f32 -> [512][512][32] f16 ----
__global__ __launch_bounds__(256) void tp_planes(
    const float* __restrict__ pxy,
    const float* __restrict__ pyz,
    const float* __restrict__ pxz,
    __half* __restrict__ ws)
{
    __shared__ float tile[32 * 132];
    unsigned bid = blockIdx.x;
    unsigned p   = bid >> 11;              // 0..2
    unsigned rem = bid & 2047u;
    unsigned y   = rem >> 2;               // 0..511
    unsigned xb  = rem & 3u;               // 4 x-tiles of 128
    const float* __restrict__ src = (p == 0) ? pxy : (p == 1) ? pyz : pxz;

    unsigned t  = threadIdx.x;
    unsigned c  = t >> 3;                  // 0..31
    unsigned xi = t & 7u;                  // 0..7
    const float* srow = src + (size_t)c * 262144u + y * 512u + xb * 128u;
#pragma unroll
    for (int i = 0; i < 4; ++i) {
        float4 v = *reinterpret_cast<const float4*>(srow + xi * 4u + i * 32u);
        *reinterpret_cast<float4*>(&tile[c * 132u + xi * 4u + i * 32u]) = v;
    }
    __syncthreads();

    unsigned xw = t >> 1;                  // 0..127
    unsigned h  = t & 1u;
    unsigned c0 = h * 16u;
    __half2 o[8];
#pragma unroll
    for (int i = 0; i < 8; ++i) {
        float a = tile[(c0 + 2u * i) * 132u + xw];
        float b = tile[(c0 + 2u * i + 1u) * 132u + xw];
        o[i] = __floats2half2_rn(a, b);
    }
    __half* dst = ws + (size_t)p * PLANE_HALVES
                + (size_t)(y * 512u + xb * 128u + xw) * 32u + c0;
    reinterpret_cast<uint4*>(dst)[0] = reinterpret_cast<const uint4*>(o)[0];
    reinterpret_cast<uint4*>(dst)[1] = reinterpret_cast<const uint4*>(o)[1];
}

// -------- transpose lines + repack W1 into f16 B-fragments -----------------------
__global__ __launch_bounds__(256) void tp_lines_w1(
    const float* __restrict__ lx, const float* __restrict__ ly,
    const float* __restrict__ lz, float* __restrict__ wl,
    const float* __restrict__ W1, __half* __restrict__ w1f)
{
    if (blockIdx.x < 192) {
        int e = blockIdx.x * 256 + threadIdx.x;   // 3*512*32 = 49152
        int l = e >> 14;
        int r = e & 16383;
        int h = r >> 5;
        int c = r & 31;
        const float* src = (l == 0) ? lx : (l == 1) ? ly : lz;
        wl[e] = src[c * 512 + h];
    } else {
        int t = threadIdx.x;
#pragma unroll
        for (int i = 0; i < 16; ++i) {
            int idx = t * 16 + i;              // 0..4095
            int e  = idx & 7;
            int ln = (idx >> 3) & 63;
            int ch = idx >> 9;
            int k = ((ln >> 4) << 3) + e;
            int n = (ch << 4) + (ln & 15);
            w1f[idx] = __float2half(W1[k * 128 + n]);
        }
    }
}

// ---------------- Morton sort machinery ------------------------------------------
__device__ inline unsigned expand5(unsigned v) {   // bit k -> bit 3k (5 bits)
    unsigned e = 0;
    e |= (v & 1u);
    e |= (v & 2u)  << 2;
    e |= (v & 4u)  << 4;
    e |= (v & 8u)  << 6;
    e |= (v & 16u) << 8;
    return e;
}

__device__ inline unsigned morton_key(float x, float y, float z) {
    // map [-1,1] -> cell 0..31 per axis
    float ux = (x + 1.0f) * 16.0f;   // [0,32)
    float uy = (y + 1.0f) * 16.0f;
    float uz = (z + 1.0f) * 16.0f;
    int cx = (int)ux; cx = cx < 0 ? 0 : (cx > 31 ? 31 : cx);
    int cy = (int)uy; cy = cy < 0 ? 0 : (cy > 31 ? 31 : cy);
    int cz = (int)uz; cz = cz < 0 ? 0 : (cz > 31 ? 31 : cz);
    return expand5((unsigned)cx) | (expand5((unsigned)cy) << 1)
         | (expand5((unsigned)cz) << 2);
}

__global__ __launch_bounds__(256) void histo_k(
    const float* __restrict__ coords, unsigned* __restrict__ hist, int P)
{
    int p = blockIdx.x * 256 + threadIdx.x;
    if (p >= P) return;
    float x = coords[3 * p + 0];
    float y = coords[3 * p + 1];
    float z = coords[3 * p + 2];
    atomicAdd(&hist[morton_key(x, y, z)], 1u);
}

// single block, 1024 threads, exclusive scan of 32768 counters in place
__global__ __launch_bounds__(1024) void scan_k(unsigned* __restrict__ hist)
{
    __shared__ unsigned ps[1024];
    int t = threadIdx.x;
    unsigned loc[32];
    unsigned s = 0;
#pragma unroll
    for (int i = 0; i < 32; ++i) { loc[i] = hist[t * 32 + i]; s += loc[i]; }
    ps[t] = s;
    __syncthreads();
    for (int off = 1; off < 1024; off <<= 1) {
        unsigned v = 0;
        if (t >= off) v = ps[t - off];
        __syncthreads();
        if (t >= off) ps[t] += v;
        __syncthreads();
    }
    unsigned run = ps[t] - s;   // exclusive base for this thread's chunk
#pragma unroll
    for (int i = 0; i < 32; ++i) { hist[t * 32 + i] = run; run += loc[i]; }
}

// scatter points into sorted order: sc[pos] = {x, y, z, bitcast(orig_idx)}
__global__ __launch_bounds__(256) void scatter_k(
    const float* __restrict__ coords, unsigned* __restrict__ cursor,
    float4* __restrict__ sc, int P)
{
    int p = blockIdx.x * 256 + threadIdx.x;
    if (p >= P) return;
    float x = coords[3 * p + 0];
    float y = coords[3 * p + 1];
    float z = coords[3 * p + 2];
    unsigned pos = atomicAdd(&cursor[morton_key(x, y, z)], 1u);
    float4 v; v.x = x; v.y = y; v.z = z; v.w = __int_as_float(p);
    sc[pos] = v;
}

// ---------------- fused sample + MFMA MLP ----------------------------------------
struct LI { int i0, i1; float w0, w1; };

__device__ inline LI mk(float g) {
    float t = (g + 1.0f) * 0.5f * 511.0f;
    float f = floorf(t);
    LI r;
    r.w1 = t - f;
    r.w0 = 1.0f - r.w1;
    int i0 = (int)f;
    i0 = i0 < 0 ? 0 : (i0 > 511 ? 511 : i0);
    r.i0 = i0;
    r.i1 = i0 < 511 ? i0 + 1 : 511;   // if i1 clamped, w1==0 -> matches zero-pad
    return r;
}

__device__ inline void load8h(const __half* __restrict__ p, float o[8]) {
    uint4 u = *reinterpret_cast<const uint4*>(p);
    __half2 h0 = *reinterpret_cast<__half2*>(&u.x);
    __half2 h1 = *reinterpret_cast<__half2*>(&u.y);
    __half2 h2 = *reinterpret_cast<__half2*>(&u.z);
    __half2 h3 = *reinterpret_cast<__half2*>(&u.w);
    float2 f0 = __half22float2(h0), f1 = __half22float2(h1);
    float2 f2 = __half22float2(h2), f3 = __half22float2(h3);
    o[0] = f0.x; o[1] = f0.y; o[2] = f1.x; o[3] = f1.y;
    o[4] = f2.x; o[5] = f2.y; o[6] = f3.x; o[7] = f3.y;
}

__device__ inline void bilerp8(const __half* __restrict__ plane,
                               const LI& Hi, const LI& Wi, int c0, float o[8]) {
    float w00 = Hi.w0 * Wi.w0, w01 = Hi.w0 * Wi.w1;
    float w10 = Hi.w1 * Wi.w0, w11 = Hi.w1 * Wi.w1;
    const __half* b00 = plane + ((size_t)(Hi.i0 * 512 + Wi.i0) * 32 + c0);
    const __half* b01 = plane + ((size_t)(Hi.i0 * 512 + Wi.i1) * 32 + c0);
    const __half* b10 = plane + ((size_t)(Hi.i1 * 512 + Wi.i0) * 32 + c0);
    const __half* b11 = plane + ((size_t)(Hi.i1 * 512 + Wi.i1) * 32 + c0);
    float v00[8], v01[8], v10[8], v11[8];
    load8h(b00, v00); load8h(b01, v01); load8h(b10, v10); load8h(b11, v11);
#pragma unroll
    for (int i = 0; i < 8; ++i)
        o[i] = v00[i] * w00 + v01[i] * w01 + v10[i] * w10 + v11[i] * w11;
}

__device__ inline void lerp8(const float* __restrict__ line,
                             const LI& L, int c0, float o[8]) {
    const float4* a = reinterpret_cast<const float4*>(line + L.i0 * 32 + c0);
    const float4* b = reinterpret_cast<const float4*>(line + L.i1 * 32 + c0);
    float4 a0 = a[0], a1 = a[1], b0 = b[0], b1 = b[1];
    o[0] = a0.x * L.w0 + b0.x * L.w1;
    o[1] = a0.y * L.w0 + b0.y * L.w1;
    o[2] = a0.z * L.w0 + b0.z * L.w1;
    o[3] = a0.w * L.w0 + b0.w * L.w1;
    o[4] = a1.x * L.w0 + b1.x * L.w1;
    o[5] = a1.y * L.w0 + b1.y * L.w1;
    o[6] = a1.z * L.w0 + b1.z * L.w1;
    o[7] = a1.w * L.w0 + b1.w * L.w1;
}

// Wave = 64 points (4 m-tiles of 16). lane = q*16 + r. Round-3 body.
// SORTED: points come from sc[] (Morton-sorted, orig idx in .w), out scattered.
// XCD-bijective swizzle keeps each XCD's L2 on a contiguous Morton range.
template<bool SORTED>
__global__ __launch_bounds__(256, 2) void tensorf_fused(
    const float* __restrict__ coords,
    const float4* __restrict__ sc,
    const __half* __restrict__ wsp,
    const float* __restrict__ wsl,
    const __half* __restrict__ w1f,
    const float* __restrict__ b1,
    const float* __restrict__ W2,
    const float* __restrict__ b2,
    float* __restrict__ out, int P, int nwg)
{
    __shared__ __align__(16) _Float16 sW1f[4096];   // 8 KB, B-fragment order
    __shared__ float sB1[128];
    __shared__ float sW2[128];
    int tid = threadIdx.x;
    reinterpret_cast<uint4*>(sW1f)[tid]       = reinterpret_cast<const uint4*>(w1f)[tid];
    reinterpret_cast<uint4*>(sW1f)[tid + 256] = reinterpret_cast<const uint4*>(w1f)[tid + 256];
    if (tid < 32)
        reinterpret_cast<float4*>(sB1)[tid] = reinterpret_cast<const float4*>(b1)[tid];
    else if (tid < 64)
        reinterpret_cast<float4*>(sW2)[tid - 32] = reinterpret_cast<const float4*>(W2)[tid - 32];
    __syncthreads();

    // bijective XCD swizzle (m204 form; nwg % 8 may be nonzero)
    int bid = blockIdx.x;
    if (SORTED) {
        int qq = nwg >> 3, rr = nwg & 7;
        int xcd = bid & 7, idx = bid >> 3;
        bid = (xcd < rr ? xcd * (qq + 1) : rr * (qq + 1) + (xcd - rr) * qq) + idx;
    }

    int lane = tid & 63;
    int wv   = tid >> 6;
    int r    = lane & 15;
    int q    = lane >> 4;
    int c0   = q * 8;
    int base = bid * 256 + wv * 64;

    const __half* pXY = wsp;                  // H from y, W from x
    const __half* pYZ = wsp + 8388608u;       // H from z, W from y
    const __half* pXZ = wsp + 16777216u;      // H from z, W from x
    const float* lX = wsl;
    const float* lY = wsl + 16384;
    const float* lZ = wsl + 32768;

    f16x8 af[4];
#pragma unroll
    for (int m = 0; m < 4; ++m) {
        int p  = base + m * 16 + r;
        int pc = p < P ? p : P - 1;
        float x, y, z;
        if (SORTED) {
            float4 v = sc[pc];
            x = v.x; y = v.y; z = v.z;
        } else {
            x = coords[3 * pc + 0];
            y = coords[3 * pc + 1];
            z = coords[3 * pc + 2];
        }
        LI ax = mk(x), ay = mk(y), az = mk(z);

        float f[8], pv[8], lv[8];
        // features = x_embed*yz + y_embed*xz + z_embed*xy
        bilerp8(pYZ, az, ay, c0, pv);
        lerp8(lX, ax, c0, lv);
#pragma unroll
        for (int i = 0; i < 8; ++i) f[i] = lv[i] * pv[i];

        bilerp8(pXZ, az, ax, c0, pv);
        lerp8(lY, ay, c0, lv);
#pragma unroll
        for (int i = 0; i < 8; ++i) f[i] = fmaf(lv[i], pv[i], f[i]);

        bilerp8(pXY, ay, ax, c0, pv);
        lerp8(lZ, az, c0, lv);
#pragma unroll
        for (int i = 0; i < 8; ++i) f[i] = fmaf(lv[i], pv[i], f[i]);

        f16x8 a;
#pragma unroll
        for (int i = 0; i < 8; ++i) a[i] = (_Float16)f[i];
        af[m] = a;
    }

    float accm[4][4];
#pragma unroll
    for (int m = 0; m < 4; ++m)
#pragma unroll
        for (int t = 0; t < 4; ++t) accm[m][t] = 0.f;

#pragma unroll
    for (int ch = 0; ch < 8; ++ch) {
        f16x8 bf = *reinterpret_cast<const f16x8*>(&sW1f[(ch * 64 + lane) * 8]);
        float bb  = sB1[ch * 16 + r];
        float w2v = sW2[ch * 16 + r];
#pragma unroll
        for (int m = 0; m < 4; ++m) {
            f32x4 cacc = {bb, bb, bb, bb};
            cacc = __builtin_amdgcn_mfma_f32_16x16x32_f16(af[m], bf, cacc, 0, 0, 0);
#pragma unroll
            for (int t = 0; t < 4; ++t) {
                float h = fmaxf(cacc[t], 0.f);
                accm[m][t] = fmaf(h, w2v, accm[m][t]);
            }
        }
    }

    // reduce over the 16 j-columns (lane&15 groups)
#pragma unroll
    for (int m = 0; m < 4; ++m)
#pragma unroll
        for (int t = 0; t < 4; ++t) {
            float v = accm[m][t];
            v += __shfl_xor(v, 1);
            v += __shfl_xor(v, 2);
            v += __shfl_xor(v, 4);
            v += __shfl_xor(v, 8);
            accm[m][t] = v;
        }

    if (r == 0) {
        float b2v = b2[0];
        const float* scf = reinterpret_cast<const float*>(sc);
#pragma unroll
        for (int m = 0; m < 4; ++m)
#pragma unroll
            for (int t = 0; t < 4; ++t) {
                int p = base + m * 16 + q * 4 + t;   // C row = q*4 + reg
                if (p < P) {
                    int op = SORTED ? __float_as_int(scf[p * 4 + 3]) : p;
                    out[op] = accm[m][t] + b2v;
                }
            }
    }
}

extern "C" void kernel_launch(void* const* d_in, const int* in_sizes, int n_in,
                              void* d_out, int out_size, void* d_ws, size_t ws_size,
                              hipStream_t stream)
{
    const float* coords   = (const float*)d_in[0];
    const float* line_x   = (const float*)d_in[1];
    const float* line_y   = (const float*)d_in[2];
    const float* line_z   = (const float*)d_in[3];
    const float* plane_xy = (const float*)d_in[4];
    const float* plane_yz = (const float*)d_in[5];
    const float* plane_xz = (const float*)d_in[6];
    const float* W1 = (const float*)d_in[7];
    const float* b1 = (const float*)d_in[8];
    const float* W2 = (const float*)d_in[9];
    const float* b2 = (const float*)d_in[10];
    int P = in_sizes[0] / 3;

    size_t planes_b = 3ull * PLANE_HALVES * 2ull;      // 48 MB
    size_t lines_b  = 3ull * 512ull * 32ull * 4ull;    // 192 KB
    size_t w1f_b    = 4096ull * 2ull;                  // 8 KB
    size_t base_need = planes_b + lines_b + w1f_b;
    size_t sc_b     = (size_t)P * 16ull;               // 16 MB
    size_t hist_b   = (size_t)NBUCKET * 4ull;          // 128 KB

    if (ws_size < base_need) return;

    __half* wsp = (__half*)d_ws;
    float*  wsl = (float*)((char*)d_ws + planes_b);
    __half* w1f = (__half*)((char*)d_ws + planes_b + lines_b);

    tp_planes<<<6144, 256, 0, stream>>>(plane_xy, plane_yz, plane_xz, wsp);
    tp_lines_w1<<<193, 256, 0, stream>>>(line_x, line_y, line_z, wsl, W1, w1f);

    int grid = (P + 255) / 256;
    bool sorted = (ws_size >= base_need + sc_b + hist_b);

    if (sorted) {
        float4*   sc   = (float4*)((char*)d_ws + base_need);
        unsigned* hist = (unsigned*)((char*)d_ws + base_need + sc_b);
        hipMemsetAsync(hist, 0, hist_b, stream);
        histo_k<<<grid, 256, 0, stream>>>(coords, hist, P);
        scan_k<<<1, 1024, 0, stream>>>(hist);
        scatter_k<<<grid, 256, 0, stream>>>(coords, hist, sc, P);
        tensorf_fused<true><<<grid, 256, 0, stream>>>(
            coords, sc, wsp, wsl, w1f, b1, W2, b2, (float*)d_out, P, grid);
    } else {
        tensorf_fused<false><<<grid, 256, 0, stream>>>(
            coords, (const float4*)nullptr, wsp, wsl, w1f, b1, W2, b2,
            (float*)d_out, P, grid);
    }
}

// Round 10
// 351.538 us; speedup vs baseline: 1.2595x; 1.2595x over previous
//
#include <hip/hip_runtime.h>
#include <hip/hip_fp16.h>
#include <stdint.h>

#define PLANE_HALVES (512u * 512u * 32u)   // 8388608 halves = 16 MB per plane

typedef _Float16 f16x8 __attribute__((ext_vector_type(8)));
typedef float    f32x4 __attribute__((ext_vector_type(4)));

// ---------------- transpose planes [C=32][512][512] f32 -> [512][512][32] f16 ----
// (r7-proven; r5 lesson: no nontemporal here)
__global__ __launch_bounds__(256) void tp_planes(
    const float* __restrict__ pxy,
    const float* __restrict__ pyz,
    const float* __restrict__ pxz,
    __half* __restrict__ ws)
{
    __shared__ float tile[32 * 132];
    unsigned bid = blockIdx.x;
    unsigned p   = bid >> 11;              // 0..2
    unsigned rem = bid & 2047u;
    unsigned y   = rem >> 2;               // 0..511
    unsigned xb  = rem & 3u;               // 4 x-tiles of 128
    const float* __restrict__ src = (p == 0) ? pxy : (p == 1) ? pyz : pxz;

    unsigned t  = threadIdx.x;
    unsigned c  = t >> 3;                  // 0..31
    unsigned xi = t & 7u;                  // 0..7
    const float* srow = src + (size_t)c * 262144u + y * 512u + xb * 128u;
#pragma unroll
    for (int i = 0; i < 4; ++i) {
        float4 v = *reinterpret_cast<const float4*>(srow + xi * 4u + i * 32u);
        *reinterpret_cast<float4*>(&tile[c * 132u + xi * 4u + i * 32u]) = v;
    }
    __syncthreads();

    unsigned xw = t >> 1;                  // 0..127
    unsigned h  = t & 1u;
    unsigned c0 = h * 16u;
    __half2 o[8];
#pragma unroll
    for (int i = 0; i < 8; ++i) {
        float a = tile[(c0 + 2u * i) * 132u + xw];
        float b = tile[(c0 + 2u * i + 1u) * 132u + xw];
        o[i] = __floats2half2_rn(a, b);
    }
    __half* dst = ws + (size_t)p * PLANE_HALVES
                + (size_t)(y * 512u + xb * 128u + xw) * 32u + c0;
    reinterpret_cast<uint4*>(dst)[0] = reinterpret_cast<const uint4*>(o)[0];
    reinterpret_cast<uint4*>(dst)[1] = reinterpret_cast<const uint4*>(o)[1];
}

// -------- line PAIR table (f16) + repack W1 into f16 B-fragments -----------------
// wl2[l*16384 + h*32 + c] = half2{ line_l[c][h], line_l[c][min(h+1,511)] }
// One 16B load of wl2 gives 4 channels x BOTH lerp rows -> 2 VMEM instr per
// line-phase instead of 4 (the kernel is VMEM-instruction-throughput bound).
__global__ __launch_bounds__(256) void tp_lines_w1(
    const float* __restrict__ lx, const float* __restrict__ ly,
    const float* __restrict__ lz, __half2* __restrict__ wl2,
    const float* __restrict__ W1, __half* __restrict__ w1f)
{
    if (blockIdx.x < 192) {
        int e = blockIdx.x * 256 + threadIdx.x;   // 0..49151
        int l = e >> 14;
        int r = e & 16383;
        int h = r >> 5;
        int c = r & 31;
        const float* src = (l == 0) ? lx : (l == 1) ? ly : lz;
        float a = src[c * 512 + h];
        float b = src[c * 512 + (h < 511 ? h + 1 : h)];
        wl2[e] = __floats2half2_rn(a, b);
    } else {
        int t = threadIdx.x;
#pragma unroll
        for (int i = 0; i < 16; ++i) {
            int idx = t * 16 + i;              // 0..4095
            int e  = idx & 7;
            int ln = (idx >> 3) & 63;
            int ch = idx >> 9;
            int k = ((ln >> 4) << 3) + e;
            int n = (ch << 4) + (ln & 15);
            w1f[idx] = __float2half(W1[k * 128 + n]);
        }
    }
}

// -------- pack coords into float4 (3 VMEM instr -> 1 in the hot kernel) ----------
__global__ __launch_bounds__(256) void tp_coords(
    const float* __restrict__ coords, float4* __restrict__ c4, int P)
{
    int p = blockIdx.x * 256 + threadIdx.x;
    if (p >= P) return;
    float4 v;
    v.x = coords[3 * p + 0];
    v.y = coords[3 * p + 1];
    v.z = coords[3 * p + 2];
    v.w = 0.f;
    c4[p] = v;
}

// ---------------- fused sample + MFMA MLP ----------------------------------------
struct LI { int i0, i1; float w0, w1; };

__device__ inline LI mk(float g) {
    float t = (g + 1.0f) * 0.5f * 511.0f;
    float f = floorf(t);
    LI r;
    r.w1 = t - f;
    r.w0 = 1.0f - r.w1;
    int i0 = (int)f;
    i0 = i0 < 0 ? 0 : (i0 > 511 ? 511 : i0);
    r.i0 = i0;
    r.i1 = i0 < 511 ? i0 + 1 : 511;   // if i1 clamped, w1==0 -> matches zero-pad
    return r;
}

__device__ inline void load8h(const __half* __restrict__ p, float o[8]) {
    uint4 u = *reinterpret_cast<const uint4*>(p);
    __half2 h0 = *reinterpret_cast<__half2*>(&u.x);
    __half2 h1 = *reinterpret_cast<__half2*>(&u.y);
    __half2 h2 = *reinterpret_cast<__half2*>(&u.z);
    __half2 h3 = *reinterpret_cast<__half2*>(&u.w);
    float2 f0 = __half22float2(h0), f1 = __half22float2(h1);
    float2 f2 = __half22float2(h2), f3 = __half22float2(h3);
    o[0] = f0.x; o[1] = f0.y; o[2] = f1.x; o[3] = f1.y;
    o[4] = f2.x; o[5] = f2.y; o[6] = f3.x; o[7] = f3.y;
}

__device__ inline void bilerp8(const __half* __restrict__ plane,
                               const LI& Hi, const LI& Wi, int c0, float o[8]) {
    float w00 = Hi.w0 * Wi.w0, w01 = Hi.w0 * Wi.w1;
    float w10 = Hi.w1 * Wi.w0, w11 = Hi.w1 * Wi.w1;
    const __half* b00 = plane + ((size_t)(Hi.i0 * 512 + Wi.i0) * 32 + c0);
    const __half* b01 = plane + ((size_t)(Hi.i0 * 512 + Wi.i1) * 32 + c0);
    const __half* b10 = plane + ((size_t)(Hi.i1 * 512 + Wi.i0) * 32 + c0);
    const __half* b11 = plane + ((size_t)(Hi.i1 * 512 + Wi.i1) * 32 + c0);
    float v00[8], v01[8], v10[8], v11[8];
    load8h(b00, v00); load8h(b01, v01); load8h(b10, v10); load8h(b11, v11);
#pragma unroll
    for (int i = 0; i < 8; ++i)
        o[i] = v00[i] * w00 + v01[i] * w01 + v10[i] * w10 + v11[i] * w11;
}

// line pair table: 2 x 16B loads give channels c0..c0+7 for rows i0 AND i0+1
__device__ inline void lerp8_pair(const __half2* __restrict__ line2,
                                  const LI& L, int c0, float o[8]) {
    const uint4* pp = reinterpret_cast<const uint4*>(line2 + L.i0 * 32 + c0);
    uint4 u0 = pp[0], u1 = pp[1];
    unsigned ua[8] = {u0.x, u0.y, u0.z, u0.w, u1.x, u1.y, u1.z, u1.w};
#pragma unroll
    for (int i = 0; i < 8; ++i) {
        __half2 h = *reinterpret_cast<__half2*>(&ua[i]);
        float2 f = __half22float2(h);     // f.x = line[i0][c], f.y = line[i0+1][c]
        o[i] = f.x * L.w0 + f.y * L.w1;
    }
}

// Wave = 64 points (4 m-tiles of 16). lane = q*16 + r. r7-passing body; only the
// line reads (pair table) and coord read (float4) changed. Launch config UNTOUCHED
// (r5/r6/r9 lesson: aggressive VGPR caps / huge LDS blocks => nondeterministic fails).
__global__ __launch_bounds__(256, 2) void tensorf_fused(
    const float* __restrict__ coords,
    const float4* __restrict__ c4,
    const __half* __restrict__ wsp,
    const __half2* __restrict__ wl2,
    const __half* __restrict__ w1f,
    const float* __restrict__ b1,
    const float* __restrict__ W2,
    const float* __restrict__ b2,
    float* __restrict__ out, int P)
{
    __shared__ __align__(16) _Float16 sW1f[4096];   // 8 KB, B-fragment order
    __shared__ float sB1[128];
    __shared__ float sW2[128];
    int tid = threadIdx.x;
    reinterpret_cast<uint4*>(sW1f)[tid]       = reinterpret_cast<const uint4*>(w1f)[tid];
    reinterpret_cast<uint4*>(sW1f)[tid + 256] = reinterpret_cast<const uint4*>(w1f)[tid + 256];
    if (tid < 32)
        reinterpret_cast<float4*>(sB1)[tid] = reinterpret_cast<const float4*>(b1)[tid];
    else if (tid < 64)
        reinterpret_cast<float4*>(sW2)[tid - 32] = reinterpret_cast<const float4*>(W2)[tid - 32];
    __syncthreads();

    int lane = tid & 63;
    int wv   = tid >> 6;
    int r    = lane & 15;
    int q    = lane >> 4;
    int c0   = q * 8;
    int base = blockIdx.x * 256 + wv * 64;

    const __half* pXY = wsp;                  // H from y, W from x
    const __half* pYZ = wsp + 8388608u;       // H from z, W from y
    const __half* pXZ = wsp + 16777216u;      // H from z, W from x
    const __half2* lX2 = wl2;
    const __half2* lY2 = wl2 + 16384;
    const __half2* lZ2 = wl2 + 32768;

    f16x8 af[4];
#pragma unroll
    for (int m = 0; m < 4; ++m) {
        int p  = base + m * 16 + r;
        int pc = p < P ? p : P - 1;
        float x, y, z;
        if (c4) {
            float4 cv = c4[pc];
            x = cv.x; y = cv.y; z = cv.z;
        } else {
            x = coords[3 * pc + 0];
            y = coords[3 * pc + 1];
            z = coords[3 * pc + 2];
        }
        LI ax = mk(x), ay = mk(y), az = mk(z);

        float f[8], pv[8], lv[8];
        // features = x_embed*yz + y_embed*xz + z_embed*xy
        bilerp8(pYZ, az, ay, c0, pv);
        lerp8_pair(lX2, ax, c0, lv);
#pragma unroll
        for (int i = 0; i < 8; ++i) f[i] = lv[i] * pv[i];

        bilerp8(pXZ, az, ax, c0, pv);
        lerp8_pair(lY2, ay, c0, lv);
#pragma unroll
        for (int i = 0; i < 8; ++i) f[i] = fmaf(lv[i], pv[i], f[i]);

        bilerp8(pXY, ay, ax, c0, pv);
        lerp8_pair(lZ2, az, c0, lv);
#pragma unroll
        for (int i = 0; i < 8; ++i) f[i] = fmaf(lv[i], pv[i], f[i]);

        f16x8 a;
#pragma unroll
        for (int i = 0; i < 8; ++i) a[i] = (_Float16)f[i];
        af[m] = a;
    }

    float accm[4][4];
#pragma unroll
    for (int m = 0; m < 4; ++m)
#pragma unroll
        for (int t = 0; t < 4; ++t) accm[m][t] = 0.f;

#pragma unroll
    for (int ch = 0; ch < 8; ++ch) {
        f16x8 bf = *reinterpret_cast<const f16x8*>(&sW1f[(ch * 64 + lane) * 8]);
        float bb  = sB1[ch * 16 + r];
        float w2v = sW2[ch * 16 + r];
#pragma unroll
        for (int m = 0; m < 4; ++m) {
            f32x4 cacc = {bb, bb, bb, bb};
            cacc = __builtin_amdgcn_mfma_f32_16x16x32_f16(af[m], bf, cacc, 0, 0, 0);
#pragma unroll
            for (int t = 0; t < 4; ++t) {
                float h = fmaxf(cacc[t], 0.f);
                accm[m][t] = fmaf(h, w2v, accm[m][t]);
            }
        }
    }

    // reduce over the 16 j-columns (lane&15 groups)
#pragma unroll
    for (int m = 0; m < 4; ++m)
#pragma unroll
        for (int t = 0; t < 4; ++t) {
            float v = accm[m][t];
            v += __shfl_xor(v, 1);
            v += __shfl_xor(v, 2);
            v += __shfl_xor(v, 4);
            v += __shfl_xor(v, 8);
            accm[m][t] = v;
        }

    if (r == 0) {
        float b2v = b2[0];
#pragma unroll
        for (int m = 0; m < 4; ++m)
#pragma unroll
            for (int t = 0; t < 4; ++t) {
                int p = base + m * 16 + q * 4 + t;   // C row = q*4 + reg
                if (p < P) out[p] = accm[m][t] + b2v;
            }
    }
}

extern "C" void kernel_launch(void* const* d_in, const int* in_sizes, int n_in,
                              void* d_out, int out_size, void* d_ws, size_t ws_size,
                              hipStream_t stream)
{
    const float* coords   = (const float*)d_in[0];
    const float* line_x   = (const float*)d_in[1];
    const float* line_y   = (const float*)d_in[2];
    const float* line_z   = (const float*)d_in[3];
    const float* plane_xy = (const float*)d_in[4];
    const float* plane_yz = (const float*)d_in[5];
    const float* plane_xz = (const float*)d_in[6];
    const float* W1 = (const float*)d_in[7];
    const float* b1 = (const float*)d_in[8];
    const float* W2 = (const float*)d_in[9];
    const float* b2 = (const float*)d_in[10];
    int P = in_sizes[0] / 3;

    size_t planes_b = 3ull * PLANE_HALVES * 2ull;      // 48 MB
    size_t w1f_b    = 4096ull * 2ull;                  // 8 KB
    size_t wl2_b    = 3ull * 512ull * 32ull * 4ull;    // 192 KB (half2)
    size_t base_need = planes_b + w1f_b + wl2_b;
    size_t c4_b     = (size_t)P * 16ull;               // 16 MB
    if (ws_size < base_need) return;

    __half*  wsp = (__half*)d_ws;
    __half*  w1f = (__half*)((char*)d_ws + planes_b);
    __half2* wl2 = (__half2*)((char*)d_ws + planes_b + w1f_b);
    bool use_c4  = (ws_size >= base_need + c4_b);
    float4*  c4  = use_c4 ? (float4*)((char*)d_ws + base_need) : (float4*)nullptr;

    tp_planes<<<6144, 256, 0, stream>>>(plane_xy, plane_yz, plane_xz, wsp);
    tp_lines_w1<<<193, 256, 0, stream>>>(line_x, line_y, line_z, wl2, W1, w1f);

    int grid = (P + 255) / 256;
    if (use_c4)
        tp_coords<<<grid, 256, 0, stream>>>(coords, c4, P);

    tensorf_fused<<<grid, 256, 0, stream>>>(coords, c4, wsp, wl2, w1f, b1, W2, b2,
                                            (float*)d_out, P);
}